// Round 7
// baseline (55905.127 us; speedup 1.0000x reference)
//
#include <hip/hip_runtime.h>
#include <math.h>

#define TSTEPS 512
#define BATCH  64
#define HDIM   1024
#define IDIM   128
#define NBLK_L 16             // blocks per layer
#define NBLOCKS (2 * NBLK_L)  // 32
#define JB     64             // j-columns per block
#define NTHR   512            // 8 waves: (m in 0..3) x (jt-pair in 0..1)

typedef __attribute__((ext_vector_type(8))) short bf16x8;
typedef __attribute__((ext_vector_type(4))) float f32x4;

// ---- ws layout (ushort units unless noted) ----
// 4 state buffers (L0 p0, L0 p1, L1 p0, L1 p1), each: hi plane [64][1024]
// (65536 ushort) then lo plane (65536). State is bf16-PAIR so A-fragments are
// 16B contiguous loads with no conversion on the consume side.
#define ST_STRIDE 131072
#define LO_OFF    65536
#define W_OFF     (4 * ST_STRIDE)
#define WI0_ELEMS 131072
#define WH_ELEMS  1048576
#define WI0HI (W_OFF)
#define WI0LO (WI0HI + WI0_ELEMS)
#define WH0HI (WI0LO + WI0_ELEMS)
#define WH0LO (WH0HI + WH_ELEMS)
#define WI1HI (WH0LO + WH_ELEMS)
#define WI1LO (WI1HI + WH_ELEMS)
#define WH1HI (WI1LO + WH_ELEMS)
#define WH1LO (WH1HI + WH_ELEMS)
#define CNT_OFF_BYTES ((size_t)(WH1LO + WH_ELEMS) * 2)  // ~14.16 MB

// ---- bf16 split helpers (RNE) ----
__device__ __forceinline__ unsigned short bf_hi(float f) {
    unsigned u = __builtin_bit_cast(unsigned, f);
    unsigned r = u + 0x7fffu + ((u >> 16) & 1u);
    return (unsigned short)(r >> 16);
}
__device__ __forceinline__ float bf_tof(unsigned short h) {
    unsigned u = ((unsigned)h) << 16;
    return __builtin_bit_cast(float, u);
}

// ---- asm loads: sc1 (coherent state) and normal-cached (weights) ----
#define GLD_SC(dst, addr) \
    asm volatile("global_load_dwordx4 %0, %1, off sc0 sc1" : "=&v"(dst) : "v"(addr))
#define GLD_NC(dst, addr) \
    asm volatile("global_load_dwordx4 %0, %1, off" : "=&v"(dst) : "v"(addr))
#define VW(N) do { \
    asm volatile("s_waitcnt vmcnt(" #N ")" ::: "memory"); \
    __builtin_amdgcn_sched_barrier(0); } while (0)

struct Frags { bf16x8 ah, al, bh0, bl0, bh1, bl1; };

// One K-stream (K = K32*32) of the pair-GEMV: acc += A * (Bh+Bl) with
// A = Ah+Al, dropping Al*Bl. A from sc1 state planes, B from cached weight
// planes. Depth-4 rotation, counted vmcnt (6 loads per kstep in flight x3).
template<int K32>
__device__ __forceinline__ void mfma_stream_sc(
    const unsigned short* Ah, const unsigned short* Al,
    const unsigned short* Bh0, const unsigned short* Bl0,
    const unsigned short* Bh1, const unsigned short* Bl1,
    f32x4& acc0, f32x4& acc1)
{
    Frags s[4];
    #pragma unroll
    for (int p = 0; p < 3; ++p) {
        GLD_SC(s[p].ah, Ah + p * 32);  GLD_SC(s[p].al, Al + p * 32);
        GLD_NC(s[p].bh0, Bh0 + p * 32); GLD_NC(s[p].bl0, Bl0 + p * 32);
        GLD_NC(s[p].bh1, Bh1 + p * 32); GLD_NC(s[p].bl1, Bl1 + p * 32);
    }
    #pragma unroll
    for (int ks = 0; ks < K32; ++ks) {
        if (ks + 3 < K32) {
            Frags& n = s[(ks + 3) & 3];
            GLD_SC(n.ah, Ah + (ks + 3) * 32);  GLD_SC(n.al, Al + (ks + 3) * 32);
            GLD_NC(n.bh0, Bh0 + (ks + 3) * 32); GLD_NC(n.bl0, Bl0 + (ks + 3) * 32);
            GLD_NC(n.bh1, Bh1 + (ks + 3) * 32); GLD_NC(n.bl1, Bl1 + (ks + 3) * 32);
            VW(18);
        } else if (ks + 2 < K32) { VW(12); }
        else if (ks + 1 < K32) { VW(6); }
        else { VW(0); }
        Frags& c = s[ks & 3];
        acc0 = __builtin_amdgcn_mfma_f32_16x16x32_bf16(c.ah, c.bh0, acc0, 0, 0, 0);
        acc1 = __builtin_amdgcn_mfma_f32_16x16x32_bf16(c.ah, c.bh1, acc1, 0, 0, 0);
        acc0 = __builtin_amdgcn_mfma_f32_16x16x32_bf16(c.al, c.bh0, acc0, 0, 0, 0);
        acc1 = __builtin_amdgcn_mfma_f32_16x16x32_bf16(c.al, c.bh1, acc1, 0, 0, 0);
        acc0 = __builtin_amdgcn_mfma_f32_16x16x32_bf16(c.ah, c.bl0, acc0, 0, 0, 0);
        acc1 = __builtin_amdgcn_mfma_f32_16x16x32_bf16(c.ah, c.bl1, acc1, 0, 0, 0);
    }
}

// x-input stream (K=128), fp32 source converted to pairs on the fly.
// Plain C++ loads: runs before any asm loads are in flight.
__device__ __forceinline__ void mfma_stream_x(
    const float* xrow,
    const unsigned short* Bh0, const unsigned short* Bl0,
    const unsigned short* Bh1, const unsigned short* Bl1,
    f32x4& acc0, f32x4& acc1)
{
    #pragma unroll
    for (int ks = 0; ks < 4; ++ks) {
        f32x4 f0 = *(const f32x4*)(xrow + ks * 32);
        f32x4 f1 = *(const f32x4*)(xrow + ks * 32 + 4);
        float fv[8] = {f0[0], f0[1], f0[2], f0[3], f1[0], f1[1], f1[2], f1[3]};
        bf16x8 ah, al;
        #pragma unroll
        for (int q = 0; q < 8; ++q) {
            unsigned short h = bf_hi(fv[q]);
            ah[q] = (short)h;
            al[q] = (short)bf_hi(fv[q] - bf_tof(h));
        }
        bf16x8 bh0 = *(const bf16x8*)(Bh0 + ks * 32);
        bf16x8 bl0 = *(const bf16x8*)(Bl0 + ks * 32);
        bf16x8 bh1 = *(const bf16x8*)(Bh1 + ks * 32);
        bf16x8 bl1 = *(const bf16x8*)(Bl1 + ks * 32);
        acc0 = __builtin_amdgcn_mfma_f32_16x16x32_bf16(ah, bh0, acc0, 0, 0, 0);
        acc1 = __builtin_amdgcn_mfma_f32_16x16x32_bf16(ah, bh1, acc1, 0, 0, 0);
        acc0 = __builtin_amdgcn_mfma_f32_16x16x32_bf16(al, bh0, acc0, 0, 0, 0);
        acc1 = __builtin_amdgcn_mfma_f32_16x16x32_bf16(al, bh1, acc1, 0, 0, 0);
        acc0 = __builtin_amdgcn_mfma_f32_16x16x32_bf16(ah, bl0, acc0, 0, 0, 0);
        acc1 = __builtin_amdgcn_mfma_f32_16x16x32_bf16(ah, bl1, acc1, 0, 0, 0);
    }
}

// Preamble (normal kernel): split the 4 fp32 weight matrices into bf16
// hi/lo planes in ws. [j][k] row-major = MFMA B-fragment layout directly.
__global__ void prep_kernel(const float* __restrict__ Wi0, const float* __restrict__ Wh0,
                            const float* __restrict__ Wi1, const float* __restrict__ Wh1,
                            unsigned short* __restrict__ wsU)
{
    const int n = WI0_ELEMS + 3 * WH_ELEMS;
    for (int e = blockIdx.x * blockDim.x + threadIdx.x; e < n;
         e += gridDim.x * blockDim.x) {
        const float* src; int idx, hiOff, loOff;
        if (e < WI0_ELEMS) { src = Wi0; idx = e; hiOff = WI0HI; loOff = WI0LO; }
        else if (e < WI0_ELEMS + WH_ELEMS) { src = Wh0; idx = e - WI0_ELEMS; hiOff = WH0HI; loOff = WH0LO; }
        else if (e < WI0_ELEMS + 2 * WH_ELEMS) { src = Wi1; idx = e - WI0_ELEMS - WH_ELEMS; hiOff = WI1HI; loOff = WI1LO; }
        else { src = Wh1; idx = e - WI0_ELEMS - 2 * WH_ELEMS; hiOff = WH1HI; loOff = WH1LO; }
        float f = src[idx];
        unsigned short h = bf_hi(f);
        wsU[hiOff + idx] = h;
        wsU[loOff + idx] = bf_hi(f - bf_tof(h));
    }
}

// Fence-free grid barrier (round-6 proven): state traffic is sc1-only so
// __syncthreads' vmcnt(0) drain + relaxed agent atomic is sufficient.
__device__ inline void grid_barrier(unsigned* cnt, unsigned target) {
    __syncthreads();
    if (threadIdx.x == 0) {
        __hip_atomic_fetch_add(cnt, 1u, __ATOMIC_RELAXED, __HIP_MEMORY_SCOPE_AGENT);
        while (__hip_atomic_load(cnt, __ATOMIC_RELAXED, __HIP_MEMORY_SCOPE_AGENT) < target)
            __builtin_amdgcn_s_sleep(1);
    }
    __syncthreads();
}

// Persistent pipeline-skewed kernel: blocks 0..15 layer 0 (step i),
// blocks 16..31 layer 1 (step i-1). Each block owns j-slice blk*64..+64,
// so h_old stays in registers across the whole scan.
__global__ __launch_bounds__(NTHR) void reservoir_kernel(
    const float* __restrict__ x, float* __restrict__ out,
    unsigned short* __restrict__ wsU)
{
    unsigned* cnt = (unsigned*)((char*)wsU + CNT_OFF_BYTES);
    const int bid = blockIdx.x;
    const int layer = (bid >= NBLK_L) ? 1 : 0;
    const int blk = layer ? (bid - NBLK_L) : bid;
    const int tid = (int)threadIdx.x, l = tid & 63;
    const int w = __builtin_amdgcn_readfirstlane(tid >> 6);
    const int m = w & 3, jtp = w >> 2;
    const int lr = l & 15, tq = l >> 4;
    const int bA = m * 16 + lr;                    // A-fragment row (batch)
    const int j0 = blk * JB + (jtp * 2 + 0) * 16 + lr;  // B column, tile 0
    const int j1 = blk * JB + (jtp * 2 + 1) * 16 + lr;  // B column, tile 1

    // zero the 1 MB state region with sc1 stores (262144 dwords / 16384 thr)
    {
        unsigned* sd = (unsigned*)wsU;
        const int base = bid * NTHR + tid;
        #pragma unroll
        for (int q = 0; q < 16; ++q)
            __hip_atomic_store(sd + base + q * 16384, 0u,
                               __ATOMIC_RELAXED, __HIP_MEMORY_SCOPE_AGENT);
    }
    grid_barrier(cnt, NBLOCKS);

    f32x4 acc0, acc1;
    float hold0[4] = {0.f, 0.f, 0.f, 0.f}, hold1[4] = {0.f, 0.f, 0.f, 0.f};

    for (int i = 0; i <= TSTEPS; ++i) {
        const int t = layer ? (i - 1) : i;
        const bool valid = layer ? (t >= 0) : (t < TSTEPS);
        if (valid) {
            #pragma unroll
            for (int q = 0; q < 4; ++q) { acc0[q] = 0.f; acc1[q] = 0.f; }

            if (!layer) {
                mfma_stream_x(x + (size_t)t * BATCH * IDIM + bA * IDIM + tq * 8,
                              wsU + WI0HI + j0 * IDIM + tq * 8, wsU + WI0LO + j0 * IDIM + tq * 8,
                              wsU + WI0HI + j1 * IDIM + tq * 8, wsU + WI0LO + j1 * IDIM + tq * 8,
                              acc0, acc1);
                const unsigned short* S = wsU + (size_t)(t & 1) * ST_STRIDE;
                mfma_stream_sc<32>(S + bA * HDIM + tq * 8, S + LO_OFF + bA * HDIM + tq * 8,
                              wsU + WH0HI + j0 * HDIM + tq * 8, wsU + WH0LO + j0 * HDIM + tq * 8,
                              wsU + WH0HI + j1 * HDIM + tq * 8, wsU + WH0LO + j1 * HDIM + tq * 8,
                              acc0, acc1);
            } else {
                const unsigned short* E = wsU + (size_t)((t + 1) & 1) * ST_STRIDE; // e0[t]
                mfma_stream_sc<32>(E + bA * HDIM + tq * 8, E + LO_OFF + bA * HDIM + tq * 8,
                              wsU + WI1HI + j0 * HDIM + tq * 8, wsU + WI1LO + j0 * HDIM + tq * 8,
                              wsU + WI1HI + j1 * HDIM + tq * 8, wsU + WI1LO + j1 * HDIM + tq * 8,
                              acc0, acc1);
                const unsigned short* S = wsU + (size_t)(2 + (t & 1)) * ST_STRIDE; // h1
                mfma_stream_sc<32>(S + bA * HDIM + tq * 8, S + LO_OFF + bA * HDIM + tq * 8,
                              wsU + WH1HI + j0 * HDIM + tq * 8, wsU + WH1LO + j0 * HDIM + tq * 8,
                              wsU + WH1HI + j1 * HDIM + tq * 8, wsU + WH1LO + j1 * HDIM + tq * 8,
                              acc0, acc1);
            }

            // epilogue: D row = (l>>4)*4 + r, col = l&15 (verified C/D layout)
            unsigned short* Wst = wsU + (size_t)(layer * 2 + ((t + 1) & 1)) * ST_STRIDE;
            #pragma unroll
            for (int r = 0; r < 4; ++r) {
                const int br = m * 16 + tq * 4 + r;
                const float h0n = 0.5f * hold0[r] + 0.5f * tanhf(acc0[r]);
                const float h1n = 0.5f * hold1[r] + 0.5f * tanhf(acc1[r]);
                hold0[r] = h0n; hold1[r] = h1n;
                unsigned short hh = bf_hi(h0n);
                unsigned short ll = bf_hi(h0n - bf_tof(hh));
                __hip_atomic_store(Wst + br * HDIM + j0, hh, __ATOMIC_RELAXED, __HIP_MEMORY_SCOPE_AGENT);
                __hip_atomic_store(Wst + LO_OFF + br * HDIM + j0, ll, __ATOMIC_RELAXED, __HIP_MEMORY_SCOPE_AGENT);
                hh = bf_hi(h1n);
                ll = bf_hi(h1n - bf_tof(hh));
                __hip_atomic_store(Wst + br * HDIM + j1, hh, __ATOMIC_RELAXED, __HIP_MEMORY_SCOPE_AGENT);
                __hip_atomic_store(Wst + LO_OFF + br * HDIM + j1, ll, __ATOMIC_RELAXED, __HIP_MEMORY_SCOPE_AGENT);
                const size_t ob = ((size_t)((size_t)t * BATCH + br) * 2 + layer) * HDIM;
                out[ob + j0] = h0n;
                out[ob + j1] = h1n;
            }
        }
        if (i < TSTEPS)
            grid_barrier(cnt, (unsigned)NBLOCKS * (unsigned)(i + 2));
    }
}

extern "C" void kernel_launch(void* const* d_in, const int* in_sizes, int n_in,
                              void* d_out, int out_size, void* d_ws, size_t ws_size,
                              hipStream_t stream) {
    const float* x   = (const float*)d_in[0];
    const float* Wi0 = (const float*)d_in[1];
    const float* Wh0 = (const float*)d_in[2];
    const float* Wi1 = (const float*)d_in[3];
    const float* Wh1 = (const float*)d_in[4];
    float* out = (float*)d_out;
    unsigned short* wsU = (unsigned short*)d_ws;

    // counter must be 0 at kernel start on EVERY replay
    hipMemsetAsync((char*)d_ws + CNT_OFF_BYTES, 0, 64, stream);
    prep_kernel<<<256, 256, 0, stream>>>(Wi0, Wh0, Wi1, Wh1, wsU);

    void* args[] = {(void*)&x, (void*)&out, (void*)&wsU};
    hipLaunchCooperativeKernel((const void*)reservoir_kernel,
                               dim3(NBLOCKS), dim3(NTHR), args, 0, stream);
}

// Round 8
// 7263.596 us; speedup vs baseline: 7.6966x; 7.6966x over previous
//
#include <hip/hip_runtime.h>
#include <math.h>

#define TSTEPS 512
#define BATCH  64
#define HDIM   1024
#define IDIM   128
#define NBLOCKS 256   // 128 per layer: (jt 0..63) x (mh 0..1)
#define NTHR   512    // 8 waves: (m2 0..1) x (kh 0..3)

typedef __attribute__((ext_vector_type(8))) short bf16x8;
typedef __attribute__((ext_vector_type(4))) float f32x4;

// ---- ws: bf16 hi/lo weight planes (ushort units), then barrier counter ----
#define WI0HI 0
#define WI0LO (WI0HI + 1024*128)
#define WH0HI (WI0LO + 1024*128)
#define WH0LO (WH0HI + 1024*1024)
#define WI1HI (WH0LO + 1024*1024)
#define WI1LO (WI1HI + 1024*1024)
#define WH1HI (WI1LO + 1024*1024)
#define WH1LO (WH1HI + 1024*1024)
#define WS_USHORTS (WH1LO + 1024*1024)
#define CNT_OFF_BYTES ((size_t)WS_USHORTS * 2)   // ~13.1 MB

// ---- LDS byte offsets: per-block 16-row weight slices, row stride K+8
// (pad 16 B -> ds_read_b128 bank-rotation, conflict-free) ----
#define L0_WI_HI 0
#define L0_WI_LO (L0_WI_HI + 16*136*2)
#define L0_WH_HI (L0_WI_LO + 16*136*2)
#define L0_WH_LO (L0_WH_HI + 16*1032*2)
#define L1_WI_HI 0
#define L1_WI_LO (L1_WI_HI + 16*1032*2)
#define L1_WH_HI (L1_WI_LO + 16*1032*2)
#define L1_WH_LO (L1_WH_HI + 16*1032*2)
#define WLDS_BYTES (L1_WH_LO + 16*1032*2)   // 132096

__device__ __forceinline__ unsigned short bf_hi(float f) {
    unsigned u = __builtin_bit_cast(unsigned, f);
    unsigned r = u + 0x7fffu + ((u >> 16) & 1u);
    return (unsigned short)(r >> 16);
}
__device__ __forceinline__ float bf_tof(unsigned short h) {
    unsigned u = ((unsigned)h) << 16;
    return __builtin_bit_cast(float, u);
}

// fp32x8 -> bf16 hi + bf16 lo fragments (RNE both; round-7-proven numerics)
__device__ __forceinline__ void split8(const float* __restrict__ p,
                                       bf16x8& ah, bf16x8& al) {
    f32x4 a = *(const f32x4*)p, b = *(const f32x4*)(p + 4);
    float fv[8] = {a[0], a[1], a[2], a[3], b[0], b[1], b[2], b[3]};
    #pragma unroll
    for (int q = 0; q < 8; ++q) {
        unsigned u = __builtin_bit_cast(unsigned, fv[q]);
        unsigned r = u + 0x7fffu + ((u >> 16) & 1u);
        ah[q] = (short)(r >> 16);
        float hf = __builtin_bit_cast(float, r & 0xffff0000u);
        float lo = fv[q] - hf;
        unsigned u2 = __builtin_bit_cast(unsigned, lo);
        al[q] = (short)((u2 + 0x7fffu + ((u2 >> 16) & 1u)) >> 16);
    }
}

// one 32-k chunk: A from global fp32 (split), B hi/lo from LDS, 3 MFMA
__device__ __forceinline__ void ks_step(const float* __restrict__ asrc,
    const unsigned char* __restrict__ lds, int hiOff, int loOff,
    int stride, int kcol, int lr, f32x4& acc)
{
    bf16x8 ah, al;
    split8(asrc, ah, al);
    const int bo = (lr * stride + kcol) * 2;
    bf16x8 bh = *(const bf16x8*)(&lds[hiOff + bo]);
    bf16x8 bl = *(const bf16x8*)(&lds[loOff + bo]);
    acc = __builtin_amdgcn_mfma_f32_16x16x32_bf16(ah, bh, acc, 0, 0, 0);
    acc = __builtin_amdgcn_mfma_f32_16x16x32_bf16(al, bh, acc, 0, 0, 0);
    acc = __builtin_amdgcn_mfma_f32_16x16x32_bf16(ah, bl, acc, 0, 0, 0);
}

template<int K>
__device__ __forceinline__ void stage_w(const unsigned short* __restrict__ g,
        unsigned char* __restrict__ lds, int ldsOff, int jbase, int tid)
{
    constexpr int TOT = 16 * K;
    #pragma unroll
    for (int base = 0; base < TOT; base += NTHR * 8) {
        const int e = base + tid * 8;
        if (TOT >= NTHR * 8 || e < TOT) {
            const int j = e / K, k = e % K;   // K pow2 -> shifts
            uint4 v = *(const uint4*)(g + (size_t)(jbase + j) * K + k);
            *(uint4*)(&lds[ldsOff + (j * (K + 8) + k) * 2]) = v;
        }
    }
}

// split fp32 weights into bf16 hi/lo planes in ws ([j][k] row-major)
__global__ void prep_kernel(const float* __restrict__ Wi0, const float* __restrict__ Wh0,
                            const float* __restrict__ Wi1, const float* __restrict__ Wh1,
                            unsigned short* __restrict__ wsU)
{
    const int n = 1024*128 + 3*1024*1024;
    for (int e = blockIdx.x * blockDim.x + threadIdx.x; e < n;
         e += gridDim.x * blockDim.x) {
        const float* src; int idx, hiOff, loOff;
        if (e < 1024*128)            { src = Wi0; idx = e;              hiOff = WI0HI; loOff = WI0LO; }
        else if (e < 1024*128 + 1024*1024)   { src = Wh0; idx = e - 1024*128;   hiOff = WH0HI; loOff = WH0LO; }
        else if (e < 1024*128 + 2*1024*1024) { src = Wi1; idx = e - 1024*128 - 1024*1024; hiOff = WI1HI; loOff = WI1LO; }
        else                         { src = Wh1; idx = e - 1024*128 - 2*1024*1024; hiOff = WH1HI; loOff = WH1LO; }
        float f = src[idx];
        unsigned short h = bf_hi(f);
        wsU[hiOff + idx] = h;
        wsU[loOff + idx] = bf_hi(f - bf_tof(h));
    }
}

// Fence-free grid barrier (round-6 proven): all cross-XCD-visible writes are
// sc1 write-through; __syncthreads drains vmcnt before the relaxed arrival.
__device__ inline void grid_barrier(unsigned* cnt, unsigned target) {
    __syncthreads();
    if (threadIdx.x == 0) {
        __hip_atomic_fetch_add(cnt, 1u, __ATOMIC_RELAXED, __HIP_MEMORY_SCOPE_AGENT);
        while (__hip_atomic_load(cnt, __ATOMIC_RELAXED, __HIP_MEMORY_SCOPE_AGENT) < target)
            __builtin_amdgcn_s_sleep(1);
    }
    __syncthreads();
}

// Persistent pipeline-skewed kernel. out[] IS the state trajectory:
// e0[t]=out[t][b][0][:], h1[t]=out[t][b][1][:]; each address written once per
// call (sc1 through) and read once (normal cached -> XCD-L2 amortized).
__global__ __launch_bounds__(NTHR) void reservoir_kernel(
    const float* __restrict__ x, float* __restrict__ out,
    const unsigned short* __restrict__ wsU, unsigned* __restrict__ cnt)
{
    __shared__ __align__(16) unsigned char wlds[WLDS_BYTES];
    __shared__ f32x4 red[8 * 64];

    const int bid = blockIdx.x;
    const int layer = bid >> 7;
    const int rr  = bid & 127;
    const int jt  = rr >> 1, mh = rr & 1;
    const int tid = (int)threadIdx.x;
    const int w   = __builtin_amdgcn_readfirstlane(tid >> 6);
    const int m2  = w & 1, kh = w >> 1;
    const int l   = tid & 63, lr = l & 15, tq = l >> 4;
    const int jbase = jt * 16;
    const int rowb  = mh * 32 + m2 * 16;   // wave's 16 A-rows (batch)

    // stage this block's weight slices into LDS once (global [j][k] planes)
    if (layer == 0) {
        stage_w<128 >(wsU + WI0HI, wlds, L0_WI_HI, jbase, tid);
        stage_w<128 >(wsU + WI0LO, wlds, L0_WI_LO, jbase, tid);
        stage_w<1024>(wsU + WH0HI, wlds, L0_WH_HI, jbase, tid);
        stage_w<1024>(wsU + WH0LO, wlds, L0_WH_LO, jbase, tid);
    } else {
        stage_w<1024>(wsU + WI1HI, wlds, L1_WI_HI, jbase, tid);
        stage_w<1024>(wsU + WI1LO, wlds, L1_WI_LO, jbase, tid);
        stage_w<1024>(wsU + WH1HI, wlds, L1_WH_HI, jbase, tid);
        stage_w<1024>(wsU + WH1LO, wlds, L1_WH_LO, jbase, tid);
    }
    __syncthreads();

    float hold[4] = {0.f, 0.f, 0.f, 0.f};   // used by finalizing waves (w<2)
    const int arow = rowb + lr;              // this lane's A row

    for (int i = 0; i <= TSTEPS; ++i) {
        const int t = layer ? (i - 1) : i;
        const bool valid = layer ? (t >= 0) : (t < TSTEPS);
        if (valid) {
            f32x4 acc = {0.f, 0.f, 0.f, 0.f};
            if (layer == 0) {
                // x part: this wave's 32-k slice of IDIM
                {
                    const int kb = kh * 32 + tq * 8;
                    ks_step(x + (size_t)t * (BATCH * IDIM) + arow * IDIM + kb,
                            wlds, L0_WI_HI, L0_WI_LO, 136, kb, lr, acc);
                }
                if (t >= 1) {   // h0[t-1] = e0[t-1] = out[t-1][.][0][.]
                    const float* h0 = out + (size_t)(t - 1) * 131072 + arow * 2048;
                    #pragma unroll 4
                    for (int ks = 0; ks < 8; ++ks) {
                        const int kb = kh * 256 + ks * 32 + tq * 8;
                        ks_step(h0 + kb, wlds, L0_WH_HI, L0_WH_LO, 1032, kb, lr, acc);
                    }
                }
            } else {
                if (kh < 2) {   // e0[t] = out[t][.][0][.]
                    const float* e0 = out + (size_t)t * 131072 + arow * 2048;
                    #pragma unroll 4
                    for (int ks = 0; ks < 16; ++ks) {
                        const int kb = kh * 512 + ks * 32 + tq * 8;
                        ks_step(e0 + kb, wlds, L1_WI_HI, L1_WI_LO, 1032, kb, lr, acc);
                    }
                } else if (t >= 1) {  // h1[t-1] = out[t-1][.][1][.]
                    const float* h1 = out + (size_t)(t - 1) * 131072 + arow * 2048 + 1024;
                    #pragma unroll 4
                    for (int ks = 0; ks < 16; ++ks) {
                        const int kb = (kh - 2) * 512 + ks * 32 + tq * 8;
                        ks_step(h1 + kb, wlds, L1_WH_HI, L1_WH_LO, 1032, kb, lr, acc);
                    }
                }
            }

            // cross-wave K-reduction (4 kh partials per (m2))
            red[w * 64 + l] = acc;
            __syncthreads();
            if (w < 2) {   // waves (m2=w, kh=0) finalize
                f32x4 s = red[(w + 0) * 64 + l];
                f32x4 s1 = red[(w + 2) * 64 + l];
                f32x4 s2 = red[(w + 4) * 64 + l];
                f32x4 s3 = red[(w + 6) * 64 + l];
                #pragma unroll
                for (int r = 0; r < 4; ++r) {
                    const float pre = ((s[r] + s1[r]) + (s2[r] + s3[r]));
                    const float hnew = 0.5f * hold[r] + 0.5f * tanhf(pre);
                    hold[r] = hnew;
                    const int row = mh * 32 + w * 16 + tq * 4 + r;   // C/D: row=(l>>4)*4+r
                    const int col = jbase + lr;                       // col=l&15
                    float* dst = out + (size_t)t * 131072 + row * 2048 + layer * 1024 + col;
                    __hip_atomic_store(dst, hnew, __ATOMIC_RELAXED, __HIP_MEMORY_SCOPE_AGENT);
                }
            }
            __syncthreads();   // red reuse safety before next superstep
        }
        if (i < TSTEPS)
            grid_barrier(cnt, (unsigned)NBLOCKS * (unsigned)(i + 1));
    }
}

extern "C" void kernel_launch(void* const* d_in, const int* in_sizes, int n_in,
                              void* d_out, int out_size, void* d_ws, size_t ws_size,
                              hipStream_t stream) {
    const float* x   = (const float*)d_in[0];
    const float* Wi0 = (const float*)d_in[1];
    const float* Wh0 = (const float*)d_in[2];
    const float* Wi1 = (const float*)d_in[3];
    const float* Wh1 = (const float*)d_in[4];
    float* out = (float*)d_out;
    unsigned short* wsU = (unsigned short*)d_ws;
    unsigned* cnt = (unsigned*)((char*)d_ws + CNT_OFF_BYTES);

    // barrier counter must be 0 at kernel start on EVERY replay
    hipMemsetAsync((char*)d_ws + CNT_OFF_BYTES, 0, 64, stream);
    prep_kernel<<<256, 256, 0, stream>>>(Wi0, Wh0, Wi1, Wh1, wsU);

    void* args[] = {(void*)&x, (void*)&out, (void*)&wsU, (void*)&cnt};
    hipLaunchCooperativeKernel((const void*)reservoir_kernel,
                               dim3(NBLOCKS), dim3(NTHR), args, 0, stream);
}

// Round 9
// 4895.374 us; speedup vs baseline: 11.4200x; 1.4838x over previous
//
#include <hip/hip_runtime.h>
#include <math.h>

#define TSTEPS 512
#define BATCH  64
#define HDIM   1024
#define IDIM   128
#define NBLOCKS 256   // 128 per layer: (jt 0..63) x (mh 0..1)
#define NTHR   512    // 8 waves: (m2 0..1) x (kh 0..3)
#define NCNT   64     // barrier counters, 64B apart (de-contended arrivals)

typedef __attribute__((ext_vector_type(8))) short bf16x8;
typedef __attribute__((ext_vector_type(4))) float f32x4;
typedef __attribute__((ext_vector_type(4))) unsigned u32x4;

// ---- ws: bf16 hi/lo weight planes (ushort units), then barrier counters ----
#define WI0HI 0
#define WI0LO (WI0HI + 1024*128)
#define WH0HI (WI0LO + 1024*128)
#define WH0LO (WH0HI + 1024*1024)
#define WI1HI (WH0LO + 1024*1024)
#define WI1LO (WI1HI + 1024*1024)
#define WH1HI (WI1LO + 1024*1024)
#define WH1LO (WH1HI + 1024*1024)
#define WS_USHORTS (WH1LO + 1024*1024)
#define CNT_OFF_BYTES ((size_t)WS_USHORTS * 2)   // 256KB-aligned

// ---- LDS byte offsets: per-block 16-row weight slices, row stride K+8 ----
#define L0_WI_HI 0
#define L0_WI_LO (L0_WI_HI + 16*136*2)
#define L0_WH_HI (L0_WI_LO + 16*136*2)
#define L0_WH_LO (L0_WH_HI + 16*1032*2)
#define L1_WI_HI 0
#define L1_WI_LO (L1_WI_HI + 16*1032*2)
#define L1_WH_HI (L1_WI_LO + 16*1032*2)
#define L1_WH_LO (L1_WH_HI + 16*1032*2)
#define WLDS_BYTES (L1_WH_LO + 16*1032*2)   // 132096

__device__ __forceinline__ unsigned short bf_hi(float f) {
    unsigned u = __builtin_bit_cast(unsigned, f);
    unsigned r = u + 0x7fffu + ((u >> 16) & 1u);
    return (unsigned short)(r >> 16);
}
__device__ __forceinline__ float bf_tof(unsigned short h) {
    unsigned u = ((unsigned)h) << 16;
    return __builtin_bit_cast(float, u);
}

// fp32x8 -> bf16 hi + lo fragments via v_cvt_pk_bf16_f32 (RNE, ~3 VALU/elem).
// lo = RNE(f - hi) captures the residual exactly; numerics = round-8 proven.
__device__ __forceinline__ void split8(const float* __restrict__ p,
                                       bf16x8& ah, bf16x8& al) {
    f32x4 a = *(const f32x4*)p, b = *(const f32x4*)(p + 4);
    float fv[8] = {a[0], a[1], a[2], a[3], b[0], b[1], b[2], b[3]};
    u32x4 H, L;
    #pragma unroll
    for (int q = 0; q < 4; ++q) {
        const float f0 = fv[2 * q], f1 = fv[2 * q + 1];
        unsigned h;
        asm("v_cvt_pk_bf16_f32 %0, %1, %2" : "=v"(h) : "v"(f0), "v"(f1));
        const float h0 = __builtin_bit_cast(float, h << 16);
        const float h1 = __builtin_bit_cast(float, h & 0xffff0000u);
        unsigned lo;
        asm("v_cvt_pk_bf16_f32 %0, %1, %2" : "=v"(lo) : "v"(f0 - h0), "v"(f1 - h1));
        H[q] = h; L[q] = lo;
    }
    ah = __builtin_bit_cast(bf16x8, H);
    al = __builtin_bit_cast(bf16x8, L);
}

// one 32-k chunk: A from global fp32 (split), B hi/lo from LDS, 3 MFMA
__device__ __forceinline__ void ks_step(const float* __restrict__ asrc,
    const unsigned char* __restrict__ lds, int hiOff, int loOff,
    int stride, int kcol, int lr, f32x4& acc)
{
    bf16x8 ah, al;
    split8(asrc, ah, al);
    const int bo = (lr * stride + kcol) * 2;
    bf16x8 bh = *(const bf16x8*)(&lds[hiOff + bo]);
    bf16x8 bl = *(const bf16x8*)(&lds[loOff + bo]);
    acc = __builtin_amdgcn_mfma_f32_16x16x32_bf16(ah, bh, acc, 0, 0, 0);
    acc = __builtin_amdgcn_mfma_f32_16x16x32_bf16(al, bh, acc, 0, 0, 0);
    acc = __builtin_amdgcn_mfma_f32_16x16x32_bf16(ah, bl, acc, 0, 0, 0);
}

template<int K>
__device__ __forceinline__ void stage_w(const unsigned short* __restrict__ g,
        unsigned char* __restrict__ lds, int ldsOff, int jbase, int tid)
{
    constexpr int TOT = 16 * K;
    #pragma unroll
    for (int base = 0; base < TOT; base += NTHR * 8) {
        const int e = base + tid * 8;
        if (TOT >= NTHR * 8 || e < TOT) {
            const int j = e / K, k = e % K;
            uint4 v = *(const uint4*)(g + (size_t)(jbase + j) * K + k);
            *(uint4*)(&lds[ldsOff + (j * (K + 8) + k) * 2]) = v;
        }
    }
}

// split fp32 weights into bf16 hi/lo planes in ws ([j][k] row-major)
__global__ void prep_kernel(const float* __restrict__ Wi0, const float* __restrict__ Wh0,
                            const float* __restrict__ Wi1, const float* __restrict__ Wh1,
                            unsigned short* __restrict__ wsU)
{
    const int n = 1024*128 + 3*1024*1024;
    for (int e = blockIdx.x * blockDim.x + threadIdx.x; e < n;
         e += gridDim.x * blockDim.x) {
        const float* src; int idx, hiOff, loOff;
        if (e < 1024*128)            { src = Wi0; idx = e;              hiOff = WI0HI; loOff = WI0LO; }
        else if (e < 1024*128 + 1024*1024)   { src = Wh0; idx = e - 1024*128;   hiOff = WH0HI; loOff = WH0LO; }
        else if (e < 1024*128 + 2*1024*1024) { src = Wi1; idx = e - 1024*128 - 1024*1024; hiOff = WI1HI; loOff = WI1LO; }
        else                         { src = Wh1; idx = e - 1024*128 - 2*1024*1024; hiOff = WH1HI; loOff = WH1LO; }
        float f = src[idx];
        unsigned short h = bf_hi(f);
        wsU[hiOff + idx] = h;
        wsU[loOff + idx] = bf_hi(f - bf_tof(h));
    }
}

// De-contended monotonic grid barrier. Arrivals spread over 64 counters
// (64B apart -> parallel MALL slices, 4-way serialization each). Wave 0
// polls all 64 with one 64-lane sc1 load; all sc1 stores drained by the
// leading __syncthreads (round-6/8-proven ordering).
__device__ __forceinline__ void grid_barrier(unsigned* cntBase, unsigned epoch) {
    __syncthreads();
    const int tid = (int)threadIdx.x;
    if (tid == 0)
        __hip_atomic_fetch_add(cntBase + (blockIdx.x & (NCNT - 1)) * 16, 1u,
                               __ATOMIC_RELAXED, __HIP_MEMORY_SCOPE_AGENT);
    if (tid < 64) {
        const unsigned tgt = (NBLOCKS / NCNT) * epoch;
        for (;;) {
            unsigned v = __hip_atomic_load(cntBase + tid * 16, __ATOMIC_RELAXED,
                                           __HIP_MEMORY_SCOPE_AGENT);
            if (__ballot(v >= tgt) == ~0ull) break;
            __builtin_amdgcn_s_sleep(1);
        }
    }
    __syncthreads();
}

// Persistent pipeline-skewed kernel. out[] IS the state trajectory:
// e0[t]=out[t][b][0][:], h1[t]=out[t][b][1][:]; each address written once per
// call (sc1 through) and read only after the ordering barrier (normal cached).
__global__ __launch_bounds__(NTHR) void reservoir_kernel(
    const float* __restrict__ x, float* __restrict__ out,
    const unsigned short* __restrict__ wsU, unsigned* __restrict__ cnt)
{
    __shared__ __align__(16) unsigned char wlds[WLDS_BYTES];
    __shared__ f32x4 red[8 * 64];

    const int bid = blockIdx.x;
    const int layer = bid >> 7;
    const int rr  = bid & 127;
    const int jt  = rr >> 1, mh = rr & 1;
    const int tid = (int)threadIdx.x;
    const int w   = __builtin_amdgcn_readfirstlane(tid >> 6);
    const int m2  = w & 1, kh = w >> 1;
    const int l   = tid & 63, lr = l & 15, tq = l >> 4;
    const int jbase = jt * 16;
    const int rowb  = mh * 32 + m2 * 16;

    if (layer == 0) {
        stage_w<128 >(wsU + WI0HI, wlds, L0_WI_HI, jbase, tid);
        stage_w<128 >(wsU + WI0LO, wlds, L0_WI_LO, jbase, tid);
        stage_w<1024>(wsU + WH0HI, wlds, L0_WH_HI, jbase, tid);
        stage_w<1024>(wsU + WH0LO, wlds, L0_WH_LO, jbase, tid);
    } else {
        stage_w<1024>(wsU + WI1HI, wlds, L1_WI_HI, jbase, tid);
        stage_w<1024>(wsU + WI1LO, wlds, L1_WI_LO, jbase, tid);
        stage_w<1024>(wsU + WH1HI, wlds, L1_WH_HI, jbase, tid);
        stage_w<1024>(wsU + WH1LO, wlds, L1_WH_LO, jbase, tid);
    }
    __syncthreads();

    float hold[4] = {0.f, 0.f, 0.f, 0.f};
    const int arow = rowb + lr;

    for (int i = 0; i <= TSTEPS; ++i) {
        const int t = layer ? (i - 1) : i;
        const bool valid = layer ? (t >= 0) : (t < TSTEPS);
        if (valid) {
            f32x4 accA = {0.f, 0.f, 0.f, 0.f};   // two chains -> MFMA ILP 2
            f32x4 accB = {0.f, 0.f, 0.f, 0.f};
            if (layer == 0) {
                {
                    const int kb = kh * 32 + tq * 8;
                    ks_step(x + (size_t)t * (BATCH * IDIM) + arow * IDIM + kb,
                            wlds, L0_WI_HI, L0_WI_LO, 136, kb, lr, accA);
                }
                if (t >= 1) {   // h0[t-1] = e0[t-1] = out[t-1][.][0][.]
                    const float* h0 = out + (size_t)(t - 1) * 131072 + arow * 2048;
                    #pragma unroll 4
                    for (int ks = 0; ks < 8; ++ks) {
                        const int kb = kh * 256 + ks * 32 + tq * 8;
                        ks_step(h0 + kb, wlds, L0_WH_HI, L0_WH_LO, 1032, kb, lr,
                                (ks & 1) ? accA : accB);
                    }
                }
            } else {
                if (kh < 2) {   // e0[t] = out[t][.][0][.]
                    const float* e0 = out + (size_t)t * 131072 + arow * 2048;
                    #pragma unroll 4
                    for (int ks = 0; ks < 16; ++ks) {
                        const int kb = kh * 512 + ks * 32 + tq * 8;
                        ks_step(e0 + kb, wlds, L1_WI_HI, L1_WI_LO, 1032, kb, lr,
                                (ks & 1) ? accA : accB);
                    }
                } else if (t >= 1) {  // h1[t-1] = out[t-1][.][1][.]
                    const float* h1 = out + (size_t)(t - 1) * 131072 + arow * 2048 + 1024;
                    #pragma unroll 4
                    for (int ks = 0; ks < 16; ++ks) {
                        const int kb = (kh - 2) * 512 + ks * 32 + tq * 8;
                        ks_step(h1 + kb, wlds, L1_WH_HI, L1_WH_LO, 1032, kb, lr,
                                (ks & 1) ? accA : accB);
                    }
                }
            }

            // cross-wave K-reduction (4 kh partials per m2)
            red[w * 64 + l] = accA + accB;
            __syncthreads();
            if (w < 2) {   // waves (m2=w, kh=0) finalize
                f32x4 s  = red[(w + 0) * 64 + l];
                f32x4 s1 = red[(w + 2) * 64 + l];
                f32x4 s2 = red[(w + 4) * 64 + l];
                f32x4 s3 = red[(w + 6) * 64 + l];
                #pragma unroll
                for (int r = 0; r < 4; ++r) {
                    const float pre = ((s[r] + s1[r]) + (s2[r] + s3[r]));
                    const float hnew = 0.5f * hold[r] + 0.5f * tanhf(pre);
                    hold[r] = hnew;
                    const int row = mh * 32 + w * 16 + tq * 4 + r;   // C/D: row=(l>>4)*4+r
                    const int col = jbase + lr;                       // col=l&15
                    float* dst = out + (size_t)t * 131072 + row * 2048 + layer * 1024 + col;
                    __hip_atomic_store(dst, hnew, __ATOMIC_RELAXED, __HIP_MEMORY_SCOPE_AGENT);
                }
            }
            __syncthreads();   // red reuse safety before next superstep
        }
        if (i < TSTEPS)
            grid_barrier(cnt, (unsigned)(i + 1));
    }
}

extern "C" void kernel_launch(void* const* d_in, const int* in_sizes, int n_in,
                              void* d_out, int out_size, void* d_ws, size_t ws_size,
                              hipStream_t stream) {
    const float* x   = (const float*)d_in[0];
    const float* Wi0 = (const float*)d_in[1];
    const float* Wh0 = (const float*)d_in[2];
    const float* Wi1 = (const float*)d_in[3];
    const float* Wh1 = (const float*)d_in[4];
    float* out = (float*)d_out;
    unsigned short* wsU = (unsigned short*)d_ws;
    unsigned* cnt = (unsigned*)((char*)d_ws + CNT_OFF_BYTES);

    // all 64 barrier counters must be 0 at kernel start on EVERY replay
    hipMemsetAsync((char*)d_ws + CNT_OFF_BYTES, 0, NCNT * 64, stream);
    prep_kernel<<<256, 256, 0, stream>>>(Wi0, Wh0, Wi1, Wh1, wsU);

    void* args[] = {(void*)&x, (void*)&out, (void*)&wsU, (void*)&cnt};
    hipLaunchCooperativeKernel((const void*)reservoir_kernel,
                               dim3(NBLOCKS), dim3(NTHR), args, 0, stream);
}

// Round 10
// 4845.639 us; speedup vs baseline: 11.5372x; 1.0103x over previous
//
#include <hip/hip_runtime.h>
#include <math.h>

#define TSTEPS 512
#define BATCH  64
#define HDIM   1024
#define IDIM   128
#define NBLOCKS 256   // 128 per layer: (jt 0..63) x (mh 0..1)
#define NTHR   512    // 8 waves: (m2 0..1) x (kh 0..3)
#define NCNT   64     // arrival counters, 64B apart

typedef __attribute__((ext_vector_type(8))) short bf16x8;
typedef __attribute__((ext_vector_type(4))) float f32x4;
typedef __attribute__((ext_vector_type(4))) unsigned u32x4;

// ---- ws: bf16 hi/lo weight planes (ushort units), then barrier area ----
#define WI0HI 0
#define WI0LO (WI0HI + 1024*128)
#define WH0HI (WI0LO + 1024*128)
#define WH0LO (WH0HI + 1024*1024)
#define WI1HI (WH0LO + 1024*1024)
#define WI1LO (WI1HI + 1024*1024)
#define WH1HI (WI1LO + 1024*1024)
#define WH1LO (WH1HI + 1024*1024)
#define WS_USHORTS (WH1LO + 1024*1024)
#define CNT_OFF_BYTES ((size_t)WS_USHORTS * 2)

__device__ __forceinline__ unsigned short bf_hi(float f) {
    unsigned u = __builtin_bit_cast(unsigned, f);
    unsigned r = u + 0x7fffu + ((u >> 16) & 1u);
    return (unsigned short)(r >> 16);
}
__device__ __forceinline__ float bf_tof(unsigned short h) {
    unsigned u = ((unsigned)h) << 16;
    return __builtin_bit_cast(float, u);
}

// fp32x8 -> bf16 hi + lo fragments via v_cvt_pk_bf16_f32 (round-9 proven)
__device__ __forceinline__ void split8(const float* __restrict__ p,
                                       bf16x8& ah, bf16x8& al) {
    f32x4 a = *(const f32x4*)p, b = *(const f32x4*)(p + 4);
    float fv[8] = {a[0], a[1], a[2], a[3], b[0], b[1], b[2], b[3]};
    u32x4 H, L;
    #pragma unroll
    for (int q = 0; q < 4; ++q) {
        const float f0 = fv[2 * q], f1 = fv[2 * q + 1];
        unsigned h;
        asm("v_cvt_pk_bf16_f32 %0, %1, %2" : "=v"(h) : "v"(f0), "v"(f1));
        const float h0 = __builtin_bit_cast(float, h << 16);
        const float h1 = __builtin_bit_cast(float, h & 0xffff0000u);
        unsigned lo;
        asm("v_cvt_pk_bf16_f32 %0, %1, %2" : "=v"(lo) : "v"(f0 - h0), "v"(f1 - h1));
        H[q] = h; L[q] = lo;
    }
    ah = __builtin_bit_cast(bf16x8, H);
    al = __builtin_bit_cast(bf16x8, L);
}

// one 32-k chunk: A from global fp32 (split), B hi/lo from REGISTERS, 3 MFMA
__device__ __forceinline__ void ks_r(const float* __restrict__ asrc,
                                     bf16x8 bh, bf16x8 bl, f32x4& acc) {
    bf16x8 ah, al;
    split8(asrc, ah, al);
    acc = __builtin_amdgcn_mfma_f32_16x16x32_bf16(ah, bh, acc, 0, 0, 0);
    acc = __builtin_amdgcn_mfma_f32_16x16x32_bf16(al, bh, acc, 0, 0, 0);
    acc = __builtin_amdgcn_mfma_f32_16x16x32_bf16(ah, bl, acc, 0, 0, 0);
}

// split fp32 weights into bf16 hi/lo planes in ws ([j][k] row-major)
__global__ void prep_kernel(const float* __restrict__ Wi0, const float* __restrict__ Wh0,
                            const float* __restrict__ Wi1, const float* __restrict__ Wh1,
                            unsigned short* __restrict__ wsU)
{
    const int n = 1024*128 + 3*1024*1024;
    for (int e = blockIdx.x * blockDim.x + threadIdx.x; e < n;
         e += gridDim.x * blockDim.x) {
        const float* src; int idx, hiOff, loOff;
        if (e < 1024*128)            { src = Wi0; idx = e;              hiOff = WI0HI; loOff = WI0LO; }
        else if (e < 1024*128 + 1024*1024)   { src = Wh0; idx = e - 1024*128;   hiOff = WH0HI; loOff = WH0LO; }
        else if (e < 1024*128 + 2*1024*1024) { src = Wi1; idx = e - 1024*128 - 1024*1024; hiOff = WI1HI; loOff = WI1LO; }
        else                         { src = Wh1; idx = e - 1024*128 - 2*1024*1024; hiOff = WH1HI; loOff = WH1LO; }
        float f = src[idx];
        unsigned short h = bf_hi(f);
        wsU[hiOff + idx] = h;
        wsU[loOff + idx] = bf_hi(f - bf_tof(h));
    }
}

// Two-phase flag barrier. Arrivals spread over 64 counters (cheap, proven);
// block 0 aggregates and publishes a single epoch flag; everyone else polls
// ONE line with one lane (kills the 64-line x 256-block poll storm).
// Ordering chain unchanged from rounds 6-9: sc1 data stores drained by the
// leading __syncthreads, then relaxed arrival; flag published only after all
// arrivals observed (data-dependent, same-thread ordered).
__device__ __forceinline__ void grid_barrier(unsigned* cntBase, unsigned epoch) {
    __syncthreads();
    const int tid = (int)threadIdx.x;
    if (tid == 0)
        __hip_atomic_fetch_add(cntBase + (blockIdx.x & (NCNT - 1)) * 16, 1u,
                               __ATOMIC_RELAXED, __HIP_MEMORY_SCOPE_AGENT);
    if (blockIdx.x == 0) {
        if (tid < 64) {
            const unsigned tgt = (NBLOCKS / NCNT) * epoch;
            for (;;) {
                unsigned v = __hip_atomic_load(cntBase + tid * 16, __ATOMIC_RELAXED,
                                               __HIP_MEMORY_SCOPE_AGENT);
                if (__ballot(v >= tgt) == ~0ull) break;
                __builtin_amdgcn_s_sleep(1);
            }
            if (tid == 0)
                __hip_atomic_store(cntBase + NCNT * 16, epoch,
                                   __ATOMIC_RELAXED, __HIP_MEMORY_SCOPE_AGENT);
        }
    } else if (tid == 0) {
        while (__hip_atomic_load(cntBase + NCNT * 16, __ATOMIC_RELAXED,
                                 __HIP_MEMORY_SCOPE_AGENT) < epoch)
            __builtin_amdgcn_s_sleep(1);
    }
    __syncthreads();
}

// Persistent pipeline-skewed kernel. out[] IS the state trajectory (round-8
// proven): e0[t]=out[t][b][0][:], h1[t]=out[t][b][1][:]; sc1 write-through
// stores, normal-cached first-touch reads. Weights live in REGISTERS per wave
// for the whole scan (<=32 bf16x8 = 128 VGPR); LDS only for the K-reduction.
__global__ __launch_bounds__(NTHR, 2) void reservoir_kernel(
    const float* __restrict__ x, float* __restrict__ out,
    const unsigned short* __restrict__ wsU, unsigned* __restrict__ cnt)
{
    __shared__ f32x4 red[8 * 64];   // 8 KB

    const int bid = blockIdx.x;
    const int layer = bid >> 7;
    const int rr  = bid & 127;
    const int jt  = rr >> 1, mh = rr & 1;
    const int tid = (int)threadIdx.x;
    const int w   = __builtin_amdgcn_readfirstlane(tid >> 6);
    const int m2  = w & 1, kh = w >> 1;
    const int l   = tid & 63, lr = l & 15, tq = l >> 4;
    const int jbase = jt * 16;
    const int arow  = mh * 32 + m2 * 16 + lr;   // this lane's A row (batch)

    // ---- load this wave's weight fragments into registers (once) ----
    bf16x8 wfh[16], wfl[16];
    if (layer == 0) {
        const size_t rx = (size_t)(jbase + lr) * IDIM + kh * 32 + tq * 8;
        wfh[0] = *(const bf16x8*)(wsU + WI0HI + rx);
        wfl[0] = *(const bf16x8*)(wsU + WI0LO + rx);
        const size_t rh = (size_t)(jbase + lr) * HDIM + kh * 256 + tq * 8;
        #pragma unroll
        for (int ks = 0; ks < 8; ++ks) {
            wfh[1 + ks] = *(const bf16x8*)(wsU + WH0HI + rh + ks * 32);
            wfl[1 + ks] = *(const bf16x8*)(wsU + WH0LO + rh + ks * 32);
        }
    } else {
        const int hiOff = (kh < 2) ? WI1HI : WH1HI;
        const int loOff = (kh < 2) ? WI1LO : WH1LO;
        const size_t ro = (size_t)(jbase + lr) * HDIM + (kh & 1) * 512 + tq * 8;
        #pragma unroll
        for (int ks = 0; ks < 16; ++ks) {
            wfh[ks] = *(const bf16x8*)(wsU + hiOff + ro + ks * 32);
            wfl[ks] = *(const bf16x8*)(wsU + loOff + ro + ks * 32);
        }
    }

    float hold[4] = {0.f, 0.f, 0.f, 0.f};

    for (int i = 0; i <= TSTEPS; ++i) {
        const int t = layer ? (i - 1) : i;
        const bool valid = layer ? (t >= 0) : (t < TSTEPS);
        if (valid) {
            f32x4 accA = {0.f, 0.f, 0.f, 0.f};
            f32x4 accB = {0.f, 0.f, 0.f, 0.f};
            if (layer == 0) {
                ks_r(x + (size_t)t * (BATCH * IDIM) + arow * IDIM + kh * 32 + tq * 8,
                     wfh[0], wfl[0], accA);
                if (t >= 1) {   // h0[t-1] = e0[t-1] = out[t-1][.][0][.]
                    const float* h0 = out + (size_t)(t - 1) * 131072 + arow * 2048
                                      + kh * 256 + tq * 8;
                    #pragma unroll
                    for (int ks = 0; ks < 8; ++ks)
                        ks_r(h0 + ks * 32, wfh[1 + ks], wfl[1 + ks],
                             (ks & 1) ? accA : accB);
                }
            } else {
                // kh<2: e0[t] x Wi1 slice; kh>=2: h1[t-1] x Wh1 slice
                const bool doit = (kh < 2) || (t >= 1);
                if (doit) {
                    const int ts  = (kh < 2) ? t : (t - 1);
                    const float* src = out + (size_t)ts * 131072 + arow * 2048
                                       + ((kh < 2) ? 0 : 1024) + (kh & 1) * 512 + tq * 8;
                    #pragma unroll
                    for (int ks = 0; ks < 16; ++ks)
                        ks_r(src + ks * 32, wfh[ks], wfl[ks],
                             (ks & 1) ? accA : accB);
                }
            }

            // cross-wave K-reduction (4 kh partials per m2)
            red[w * 64 + l] = accA + accB;
            __syncthreads();
            if (w < 2) {   // waves (m2=w, kh=0) finalize
                f32x4 s  = red[(w + 0) * 64 + l];
                f32x4 s1 = red[(w + 2) * 64 + l];
                f32x4 s2 = red[(w + 4) * 64 + l];
                f32x4 s3 = red[(w + 6) * 64 + l];
                #pragma unroll
                for (int r = 0; r < 4; ++r) {
                    const float pre = ((s[r] + s1[r]) + (s2[r] + s3[r]));
                    const float hnew = 0.5f * hold[r] + 0.5f * tanhf(pre);
                    hold[r] = hnew;
                    const int row = mh * 32 + w * 16 + tq * 4 + r;   // C/D: row=(l>>4)*4+r
                    const int col = jbase + lr;                       // col=l&15
                    float* dst = out + (size_t)t * 131072 + row * 2048 + layer * 1024 + col;
                    __hip_atomic_store(dst, hnew, __ATOMIC_RELAXED, __HIP_MEMORY_SCOPE_AGENT);
                }
            }
            __syncthreads();   // red reuse safety
        }
        if (i < TSTEPS)
            grid_barrier(cnt, (unsigned)(i + 1));
    }
}

extern "C" void kernel_launch(void* const* d_in, const int* in_sizes, int n_in,
                              void* d_out, int out_size, void* d_ws, size_t ws_size,
                              hipStream_t stream) {
    const float* x   = (const float*)d_in[0];
    const float* Wi0 = (const float*)d_in[1];
    const float* Wh0 = (const float*)d_in[2];
    const float* Wi1 = (const float*)d_in[3];
    const float* Wh1 = (const float*)d_in[4];
    float* out = (float*)d_out;
    unsigned short* wsU = (unsigned short*)d_ws;
    unsigned* cnt = (unsigned*)((char*)d_ws + CNT_OFF_BYTES);

    // counters + flag must be 0 at kernel start on EVERY replay
    hipMemsetAsync((char*)d_ws + CNT_OFF_BYTES, 0, NCNT * 64 + 64, stream);
    prep_kernel<<<256, 256, 0, stream>>>(Wi0, Wh0, Wi1, Wh1, wsU);

    void* args[] = {(void*)&x, (void*)&out, (void*)&wsU, (void*)&cnt};
    hipLaunchCooperativeKernel((const void*)reservoir_kernel,
                               dim3(NBLOCKS), dim3(NTHR), args, 0, stream);
}

// Round 11
// 4718.381 us; speedup vs baseline: 11.8484x; 1.0270x over previous
//
#include <hip/hip_runtime.h>
#include <math.h>

#define TSTEPS 512
#define BATCH  64
#define HDIM   1024
#define IDIM   128
#define NBLOCKS 256   // 128 per layer: (jt 0..63) x (mh 0..1)
#define NTHR   512    // 8 waves: (m2 0..1) x (kh 0..3)

typedef __attribute__((ext_vector_type(8))) short bf16x8;
typedef __attribute__((ext_vector_type(4))) float f32x4;
typedef __attribute__((ext_vector_type(4))) unsigned u32x4;

// ---- ws: bf16 hi/lo weight planes (ushort units), then barrier area ----
#define WI0HI 0
#define WI0LO (WI0HI + 1024*128)
#define WH0HI (WI0LO + 1024*128)
#define WH0LO (WH0HI + 1024*1024)
#define WI1HI (WH0LO + 1024*1024)
#define WI1LO (WI1HI + 1024*1024)
#define WH1HI (WI1LO + 1024*1024)
#define WH1LO (WH1HI + 1024*1024)
#define WS_USHORTS (WH1LO + 1024*1024)
#define CNT_OFF_BYTES ((size_t)WS_USHORTS * 2)
// barrier area (dword offsets from cnt): arrivals 256 x 16, flags 256 x 16
#define FLG_DW (256 * 16)
#define BAR_BYTES (2 * 256 * 64)   // 32 KB

__device__ __forceinline__ unsigned short bf_hi(float f) {
    unsigned u = __builtin_bit_cast(unsigned, f);
    unsigned r = u + 0x7fffu + ((u >> 16) & 1u);
    return (unsigned short)(r >> 16);
}
__device__ __forceinline__ float bf_tof(unsigned short h) {
    unsigned u = ((unsigned)h) << 16;
    return __builtin_bit_cast(float, u);
}

// fp32x8 -> bf16 hi + lo fragments via v_cvt_pk_bf16_f32 (round-9/10 proven)
__device__ __forceinline__ void split8(const float* __restrict__ p,
                                       bf16x8& ah, bf16x8& al) {
    f32x4 a = *(const f32x4*)p, b = *(const f32x4*)(p + 4);
    float fv[8] = {a[0], a[1], a[2], a[3], b[0], b[1], b[2], b[3]};
    u32x4 H, L;
    #pragma unroll
    for (int q = 0; q < 4; ++q) {
        const float f0 = fv[2 * q], f1 = fv[2 * q + 1];
        unsigned h;
        asm("v_cvt_pk_bf16_f32 %0, %1, %2" : "=v"(h) : "v"(f0), "v"(f1));
        const float h0 = __builtin_bit_cast(float, h << 16);
        const float h1 = __builtin_bit_cast(float, h & 0xffff0000u);
        unsigned lo;
        asm("v_cvt_pk_bf16_f32 %0, %1, %2" : "=v"(lo) : "v"(f0 - h0), "v"(f1 - h1));
        H[q] = h; L[q] = lo;
    }
    ah = __builtin_bit_cast(bf16x8, H);
    al = __builtin_bit_cast(bf16x8, L);
}

// one 32-k chunk: A from global fp32 (split), B hi/lo from REGISTERS, 3 MFMA
__device__ __forceinline__ void ks_r(const float* __restrict__ asrc,
                                     bf16x8 bh, bf16x8 bl, f32x4& acc) {
    bf16x8 ah, al;
    split8(asrc, ah, al);
    acc = __builtin_amdgcn_mfma_f32_16x16x32_bf16(ah, bh, acc, 0, 0, 0);
    acc = __builtin_amdgcn_mfma_f32_16x16x32_bf16(al, bh, acc, 0, 0, 0);
    acc = __builtin_amdgcn_mfma_f32_16x16x32_bf16(ah, bl, acc, 0, 0, 0);
}

// split fp32 weights into bf16 hi/lo planes in ws ([j][k] row-major)
__global__ void prep_kernel(const float* __restrict__ Wi0, const float* __restrict__ Wh0,
                            const float* __restrict__ Wi1, const float* __restrict__ Wh1,
                            unsigned short* __restrict__ wsU)
{
    const int n = 1024*128 + 3*1024*1024;
    for (int e = blockIdx.x * blockDim.x + threadIdx.x; e < n;
         e += gridDim.x * blockDim.x) {
        const float* src; int idx, hiOff, loOff;
        if (e < 1024*128)            { src = Wi0; idx = e;              hiOff = WI0HI; loOff = WI0LO; }
        else if (e < 1024*128 + 1024*1024)   { src = Wh0; idx = e - 1024*128;   hiOff = WH0HI; loOff = WH0LO; }
        else if (e < 1024*128 + 2*1024*1024) { src = Wi1; idx = e - 1024*128 - 1024*1024; hiOff = WI1HI; loOff = WI1LO; }
        else                         { src = Wh1; idx = e - 1024*128 - 2*1024*1024; hiOff = WH1HI; loOff = WH1LO; }
        float f = src[idx];
        unsigned short h = bf_hi(f);
        wsU[hiOff + idx] = h;
        wsU[loOff + idx] = bf_hi(f - bf_tof(h));
    }
}

// --- One-reader-per-line grid barrier (contention-free MALL protocol) ---
// arrive: block stores epoch to its OWN arrival line (no atomics, no sharing).
// wait:   block 0 sweeps all 256 arrival lines (4 x 64-lane loads; sole
//         reader), then writes 256 per-block flag lines (4 stores, parallel
//         MALL slices). Every other block polls ITS OWN flag line (1 reader).
// Ordering chain unchanged from rounds 6-10: sc1 data stores drained by the
// arrive-side __syncthreads; epochs monotonic; flags published only after all
// arrivals observed (program-ordered after the poll loop's loads complete).
__device__ __forceinline__ void barrier_arrive(unsigned* cnt, unsigned epoch) {
    __syncthreads();   // drain all waves' sc1 data stores (vmcnt 0)
    if (threadIdx.x == 0)
        __hip_atomic_store(cnt + (unsigned)blockIdx.x * 16, epoch,
                           __ATOMIC_RELAXED, __HIP_MEMORY_SCOPE_AGENT);
}
__device__ __forceinline__ void barrier_wait(unsigned* cnt, unsigned epoch) {
    const int tid = (int)threadIdx.x;
    if (blockIdx.x == 0) {
        if (tid < 64) {
            unsigned* flg = cnt + FLG_DW;
            for (;;) {
                unsigned v0 = __hip_atomic_load(cnt + (tid      ) * 16, __ATOMIC_RELAXED, __HIP_MEMORY_SCOPE_AGENT);
                unsigned v1 = __hip_atomic_load(cnt + (tid +  64) * 16, __ATOMIC_RELAXED, __HIP_MEMORY_SCOPE_AGENT);
                unsigned v2 = __hip_atomic_load(cnt + (tid + 128) * 16, __ATOMIC_RELAXED, __HIP_MEMORY_SCOPE_AGENT);
                unsigned v3 = __hip_atomic_load(cnt + (tid + 192) * 16, __ATOMIC_RELAXED, __HIP_MEMORY_SCOPE_AGENT);
                bool ok = (v0 >= epoch) & (v1 >= epoch) & (v2 >= epoch) & (v3 >= epoch);
                if (__ballot(ok) == ~0ull) break;
                __builtin_amdgcn_s_sleep(1);
            }
            #pragma unroll
            for (int q = 0; q < 4; ++q)
                __hip_atomic_store(flg + (q * 64 + tid) * 16, epoch,
                                   __ATOMIC_RELAXED, __HIP_MEMORY_SCOPE_AGENT);
        }
    } else if (tid == 0) {
        unsigned* myflag = cnt + FLG_DW + (unsigned)blockIdx.x * 16;
        while (__hip_atomic_load(myflag, __ATOMIC_RELAXED,
                                 __HIP_MEMORY_SCOPE_AGENT) < epoch)
            __builtin_amdgcn_s_sleep(1);
    }
    __syncthreads();
}

// Persistent pipeline-skewed kernel. out[] IS the state trajectory (round-8
// proven): e0[t]=out[t][b][0][:], h1[t]=out[t][b][1][:]; sc1 write-through
// stores, normal-cached first-touch reads. Weights live in REGISTERS per wave
// for the whole scan; LDS only for the K-reduction.
__global__ __launch_bounds__(NTHR, 2) void reservoir_kernel(
    const float* __restrict__ x, float* __restrict__ out,
    const unsigned short* __restrict__ wsU, unsigned* __restrict__ cnt)
{
    __shared__ f32x4 red[8 * 64];   // 8 KB

    const int bid = blockIdx.x;
    const int layer = bid >> 7;
    const int rr  = bid & 127;
    const int jt  = rr >> 1, mh = rr & 1;
    const int tid = (int)threadIdx.x;
    const int w   = __builtin_amdgcn_readfirstlane(tid >> 6);
    const int m2  = w & 1, kh = w >> 1;
    const int l   = tid & 63, lr = l & 15, tq = l >> 4;
    const int jbase = jt * 16;
    const int arow  = mh * 32 + m2 * 16 + lr;   // this lane's A row (batch)

    // ---- load this wave's weight fragments into registers (once) ----
    bf16x8 wfh[16], wfl[16];
    if (layer == 0) {
        const size_t rx = (size_t)(jbase + lr) * IDIM + kh * 32 + tq * 8;
        wfh[0] = *(const bf16x8*)(wsU + WI0HI + rx);
        wfl[0] = *(const bf16x8*)(wsU + WI0LO + rx);
        const size_t rh = (size_t)(jbase + lr) * HDIM + kh * 256 + tq * 8;
        #pragma unroll
        for (int ks = 0; ks < 8; ++ks) {
            wfh[1 + ks] = *(const bf16x8*)(wsU + WH0HI + rh + ks * 32);
            wfl[1 + ks] = *(const bf16x8*)(wsU + WH0LO + rh + ks * 32);
        }
    } else {
        const int hiOff = (kh < 2) ? WI1HI : WH1HI;
        const int loOff = (kh < 2) ? WI1LO : WH1LO;
        const size_t ro = (size_t)(jbase + lr) * HDIM + (kh & 1) * 512 + tq * 8;
        #pragma unroll
        for (int ks = 0; ks < 16; ++ks) {
            wfh[ks] = *(const bf16x8*)(wsU + hiOff + ro + ks * 32);
            wfl[ks] = *(const bf16x8*)(wsU + loOff + ro + ks * 32);
        }
    }

    float hold[4] = {0.f, 0.f, 0.f, 0.f};
    f32x4 accX = {0.f, 0.f, 0.f, 0.f};   // layer-0 x-part prefetch

    for (int i = 0; i <= TSTEPS; ++i) {
        const int t = layer ? (i - 1) : i;
        const bool valid = layer ? (t >= 0) : (t < TSTEPS);
        if (valid) {
            f32x4 accA = {0.f, 0.f, 0.f, 0.f};
            f32x4 accB = {0.f, 0.f, 0.f, 0.f};
            if (layer == 0) {
                if (i == 0) {
                    ks_r(x + (size_t)t * (BATCH * IDIM) + arow * IDIM + kh * 32 + tq * 8,
                         wfh[0], wfl[0], accA);
                } else {
                    accA = accX;   // prefetched under the previous barrier
                }
                if (t >= 1) {   // h0[t-1] = e0[t-1] = out[t-1][.][0][.]
                    const float* h0 = out + (size_t)(t - 1) * 131072 + arow * 2048
                                      + kh * 256 + tq * 8;
                    #pragma unroll
                    for (int ks = 0; ks < 8; ++ks)
                        ks_r(h0 + ks * 32, wfh[1 + ks], wfl[1 + ks],
                             (ks & 1) ? accA : accB);
                }
            } else {
                // kh<2: e0[t] x Wi1 slice; kh>=2: h1[t-1] x Wh1 slice
                const bool doit = (kh < 2) || (t >= 1);
                if (doit) {
                    const int ts  = (kh < 2) ? t : (t - 1);
                    const float* src = out + (size_t)ts * 131072 + arow * 2048
                                       + ((kh < 2) ? 0 : 1024) + (kh & 1) * 512 + tq * 8;
                    #pragma unroll
                    for (int ks = 0; ks < 16; ++ks)
                        ks_r(src + ks * 32, wfh[ks], wfl[ks],
                             (ks & 1) ? accA : accB);
                }
            }

            // cross-wave K-reduction (4 kh partials per m2)
            red[w * 64 + l] = accA + accB;
            __syncthreads();
            if (w < 2) {   // waves (m2=w, kh=0) finalize
                f32x4 s  = red[(w + 0) * 64 + l];
                f32x4 s1 = red[(w + 2) * 64 + l];
                f32x4 s2 = red[(w + 4) * 64 + l];
                f32x4 s3 = red[(w + 6) * 64 + l];
                #pragma unroll
                for (int r = 0; r < 4; ++r) {
                    const float pre = ((s[r] + s1[r]) + (s2[r] + s3[r]));
                    const float hnew = 0.5f * hold[r] + 0.5f * tanhf(pre);
                    hold[r] = hnew;
                    const int row = mh * 32 + w * 16 + tq * 4 + r;   // C/D: row=(l>>4)*4+r
                    const int col = jbase + lr;                       // col=l&15
                    float* dst = out + (size_t)t * 131072 + row * 2048 + layer * 1024 + col;
                    __hip_atomic_store(dst, hnew, __ATOMIC_RELAXED, __HIP_MEMORY_SCOPE_AGENT);
                }
            }
            __syncthreads();   // red reuse safety
        }
        if (i < TSTEPS) {
            barrier_arrive(cnt, (unsigned)(i + 1));
            // overlap: layer-0's x-part for step i+1 is barrier-independent
            if (layer == 0 && (i + 1) < TSTEPS) {
                f32x4 z = {0.f, 0.f, 0.f, 0.f};
                ks_r(x + (size_t)(i + 1) * (BATCH * IDIM) + arow * IDIM + kh * 32 + tq * 8,
                     wfh[0], wfl[0], z);
                accX = z;
            }
            barrier_wait(cnt, (unsigned)(i + 1));
        }
    }
}

extern "C" void kernel_launch(void* const* d_in, const int* in_sizes, int n_in,
                              void* d_out, int out_size, void* d_ws, size_t ws_size,
                              hipStream_t stream) {
    const float* x   = (const float*)d_in[0];
    const float* Wi0 = (const float*)d_in[1];
    const float* Wh0 = (const float*)d_in[2];
    const float* Wi1 = (const float*)d_in[3];
    const float* Wh1 = (const float*)d_in[4];
    float* out = (float*)d_out;
    unsigned short* wsU = (unsigned short*)d_ws;
    unsigned* cnt = (unsigned*)((char*)d_ws + CNT_OFF_BYTES);

    // arrival + flag lines must be 0 at kernel start on EVERY replay
    hipMemsetAsync((char*)d_ws + CNT_OFF_BYTES, 0, BAR_BYTES, stream);
    prep_kernel<<<256, 256, 0, stream>>>(Wi0, Wh0, Wi1, Wh1, wsU);

    void* args[] = {(void*)&x, (void*)&out, (void*)&wsU, (void*)&cnt};
    hipLaunchCooperativeKernel((const void*)reservoir_kernel,
                               dim3(NBLOCKS), dim3(NTHR), args, 0, stream);
}